// Round 1
// baseline (975.309 us; speedup 1.0000x reference)
//
#include <hip/hip_runtime.h>

#define NTOK 131072
#define NEXP 8
#define NDIM 128

typedef __bf16 bf16x8 __attribute__((ext_vector_type(8)));
typedef float f32x4 __attribute__((ext_vector_type(4)));
typedef unsigned short u16x8 __attribute__((ext_vector_type(8)));

union PackAB { u16x8 u; bf16x8 b; };

__device__ __forceinline__ unsigned short f2bf(float f) {
    unsigned int u = __float_as_uint(f);
    u += 0x7FFFu + ((u >> 16) & 1u);   // round-to-nearest-even
    return (unsigned short)(u >> 16);
}

// Each block: 128 tokens (blockIdx.x) x 1 expert (blockIdx.y).
// 4 waves, each wave computes 32 rows x 128 cols via 16x16x32 bf16 MFMA.
__global__ __launch_bounds__(256) void seq_experts_kernel(
    const float* __restrict__ inp,   // [N, E, D] fp32
    const float* __restrict__ W,     // [E, D, D] fp32 (d-major rows, f contiguous)
    const float* __restrict__ bias,  // [E, D]
    float* __restrict__ out)         // [N, E, D] fp32
{
    // W^T (f-major, d contiguous) as bf16, XOR-swizzled k-blocks:
    // element (f,d) at ushort index  f*128 + (((d>>3) ^ (f&15))<<3) + (d&7)
    __shared__ unsigned short Wt[NDIM * NDIM];   // 32 KiB

    const int e    = blockIdx.y;
    const int tid  = threadIdx.x;
    const int wave = tid >> 6;
    const int lane = tid & 63;
    const int quad = lane >> 4;
    const int l16  = lane & 15;

    // ---- stage W[e]^T -> LDS (bf16, swizzled) ----
    {
        const float* We = W + (size_t)e * (NDIM * NDIM);
        const int f    = tid & 127;   // lanes have consecutive f -> coalesced reads
        const int half = tid >> 7;    // 0/1: which 8 k-blocks this thread covers
        #pragma unroll
        for (int kb = 0; kb < 8; ++kb) {
            const int KB = half * 8 + kb;          // d-block 0..15
            PackAB pk;
            #pragma unroll
            for (int j = 0; j < 8; ++j)
                pk.u[j] = f2bf(We[(size_t)(KB * 8 + j) * NDIM + f]);
            *(u16x8*)&Wt[f * NDIM + ((KB ^ (f & 15)) << 3)] = pk.u;
        }
    }

    // ---- A fragments straight from global, fp32 -> bf16 ----
    // A-operand layout (16x16x32): lane holds A[m=lane&15][k=quad*8+j]
    const int rowbase = blockIdx.x * 128 + wave * 32;
    bf16x8 afrag[2][4];
    #pragma unroll
    for (int rt = 0; rt < 2; ++rt) {
        const int n = rowbase + rt * 16 + l16;
        const float* arow = inp + ((size_t)n * NEXP + e) * NDIM;
        #pragma unroll
        for (int ks = 0; ks < 4; ++ks) {
            const float* p = arow + ks * 32 + quad * 8;
            float4 x = *(const float4*)(p);
            float4 y = *(const float4*)(p + 4);
            PackAB pk;
            pk.u[0] = f2bf(x.x); pk.u[1] = f2bf(x.y);
            pk.u[2] = f2bf(x.z); pk.u[3] = f2bf(x.w);
            pk.u[4] = f2bf(y.x); pk.u[5] = f2bf(y.y);
            pk.u[6] = f2bf(y.z); pk.u[7] = f2bf(y.w);
            afrag[rt][ks] = pk.b;
        }
    }

    __syncthreads();

    // ---- MFMA main loop: 4 k-steps x 8 col-tiles x 2 row-tiles ----
    f32x4 acc[2][8] = {};
    #pragma unroll
    for (int ks = 0; ks < 4; ++ks) {
        const int kb = ks * 4 + quad;            // k-block this lane's B frag needs
        #pragma unroll
        for (int ct = 0; ct < 8; ++ct) {
            const int f = ct * 16 + l16;
            PackAB pk;
            pk.u = *(const u16x8*)&Wt[f * NDIM + ((kb ^ l16) << 3)];
            const bf16x8 bfrag = pk.b;
            acc[0][ct] = __builtin_amdgcn_mfma_f32_16x16x32_bf16(afrag[0][ks], bfrag, acc[0][ct], 0, 0, 0);
            acc[1][ct] = __builtin_amdgcn_mfma_f32_16x16x32_bf16(afrag[1][ks], bfrag, acc[1][ct], 0, 0, 0);
        }
    }

    // ---- epilogue: bias + store (C/D layout: col=lane&15, row=quad*4+reg) ----
    const float* be = bias + e * NDIM;
    #pragma unroll
    for (int ct = 0; ct < 8; ++ct) {
        const float bv = be[ct * 16 + l16];
        #pragma unroll
        for (int rt = 0; rt < 2; ++rt) {
            const int n0 = rowbase + rt * 16 + quad * 4;
            float* po = out + ((size_t)n0 * NEXP + e) * NDIM + ct * 16 + l16;
            #pragma unroll
            for (int r = 0; r < 4; ++r)
                po[(size_t)r * (NEXP * NDIM)] = acc[rt][ct][r] + bv;
        }
    }
}

extern "C" void kernel_launch(void* const* d_in, const int* in_sizes, int n_in,
                              void* d_out, int out_size, void* d_ws, size_t ws_size,
                              hipStream_t stream) {
    const float* inp  = (const float*)d_in[0];
    const float* W    = (const float*)d_in[1];
    const float* bb   = (const float*)d_in[2];
    float* out = (float*)d_out;
    dim3 grid(NTOK / 128, NEXP);
    seq_experts_kernel<<<grid, dim3(256), 0, stream>>>(inp, W, bb, out);
}